// Round 1
// 359.471 us; speedup vs baseline: 1.0755x; 1.0755x over previous
//
#include <hip/hip_runtime.h>
#include <hip/hip_bf16.h>
#include <cstdint>
#include <cstddef>

// YatDense: out[m,n] = (y^2 / (|x_m|^2 + |w_n|^2 - 2y + eps)) * scale + bias[n]
//   y = x[m,:] . w[n,:]   GEMM M=16384, N=2048, K=2048 (B^T layout input)
// R6: port the 8-phase 256x256 schedule (T2+T3+T4+T5) to replace the m97-style
// 2-barrier loop (which plateaus at ~810 TF / MfmaUtil 36%).
//  - BM=BN=256, BK=64, 8 waves (2x4), each wave owns a 128x64 C-tile.
//  - LDS = 128 KiB ring: 4 A-segs + 4 B-segs, seg = [128 rows][64 k] bf16
//    (16 KB). Seg slot for (kt,half) = (2*kt+half)&3, double-buffered.
//  - Per iteration (2 K-tiles, 8 phases): each phase {ds_read frags | stage
//    one seg (2x global_load_lds w=16) | s_barrier | setprio(1) 16 MFMA
//    setprio(0) | counted vmcnt at ph4/ph8 | s_barrier}. Never vmcnt(0) in
//    steady state -> prefetched segs stay in flight across barriers.
//  - XOR swizzle: LDS phys 16B-chunk c of seg row r holds global chunk
//    c^(r&7); reads apply same XOR -> ds_read_b128 conflict-free.
//    global_load_lds dest stays linear; the global SOURCE is pre-permuted.
//  - Stage schedule (iter u, a=2u, b=2u+1): p1 A(b,0) p2 A(b,1) p3 B(a+2,0)
//    p4 B(a+2,1)+vmcnt(4) p5 A(a+2,0) p6 A(a+2,1) p7 B(b+2,0) p8 B(b+2,1)
//    +vmcnt(4). Every stage targets a slot whose last read completed before
//    the previous phase's closing barrier; vmcnt(4)+barrier at p4/p8 makes
//    the next phase's segs visible across waves. Tail iter: vmcnt(0).

typedef __bf16 bf16_t;
typedef __bf16 bf16x8 __attribute__((ext_vector_type(8)));
typedef __bf16 bf16x4 __attribute__((ext_vector_type(4)));
typedef float f32x4 __attribute__((ext_vector_type(4)));

constexpr int M_DIM = 16384;  // B*S
constexpr int N_DIM = 2048;   // F
constexpr int K_DIM = 2048;   // D
constexpr int BM = 256, BN = 256, BK = 64;
constexpr int KT = K_DIM / BK;  // 32 K-tiles
constexpr int SEG = 128 * 64;   // seg elements (16 KB)

__device__ __forceinline__ void async16(const bf16_t* g, bf16_t* l) {
    __builtin_amdgcn_global_load_lds(
        (const __attribute__((address_space(1))) void*)g,
        (__attribute__((address_space(3))) void*)l,
        16, 0, 0);
}

// ---------------------------------------------------------------------------
// prep: one block per row (x rows [0,M), w rows [M,M+N)).
// Reads 2048 fp32, writes 2048 bf16 (RNE), computes fp32 sum of squares.
// (unchanged from R5 — kept identical to isolate the GEMM change)
// ---------------------------------------------------------------------------
__global__ __launch_bounds__(256) void prep_convert(const float* __restrict__ x,
                                                    const float* __restrict__ w,
                                                    bf16_t* __restrict__ xb,
                                                    bf16_t* __restrict__ wb,
                                                    float* __restrict__ xsq,
                                                    float* __restrict__ wsq) {
    const int row = blockIdx.x;
    const float* src;
    bf16_t* dstb;
    float* dsts;
    if (row < M_DIM) {
        src = x + (size_t)row * K_DIM;
        dstb = xb + (size_t)row * K_DIM;
        dsts = xsq + row;
    } else {
        const int r = row - M_DIM;
        src = w + (size_t)r * K_DIM;
        dstb = wb + (size_t)r * K_DIM;
        dsts = wsq + r;
    }
    const float4* s4 = (const float4*)src;
    const float4 a = s4[threadIdx.x];
    const float4 b = s4[threadIdx.x + 256];
    float s = a.x * a.x + a.y * a.y + a.z * a.z + a.w * a.w
            + b.x * b.x + b.y * b.y + b.z * b.z + b.w * b.w;
    bf16x4 av = { (bf16_t)a.x, (bf16_t)a.y, (bf16_t)a.z, (bf16_t)a.w };
    bf16x4 bv = { (bf16_t)b.x, (bf16_t)b.y, (bf16_t)b.z, (bf16_t)b.w };
    ((bf16x4*)dstb)[threadIdx.x] = av;
    ((bf16x4*)dstb)[threadIdx.x + 256] = bv;
#pragma unroll
    for (int off = 32; off > 0; off >>= 1) s += __shfl_down(s, off, 64);
    __shared__ float red[4];
    const int lane = threadIdx.x & 63;
    const int wv = threadIdx.x >> 6;
    if (lane == 0) red[wv] = s;
    __syncthreads();
    if (threadIdx.x == 0) *dsts = red[0] + red[1] + red[2] + red[3];
}

// ---------------------------------------------------------------------------
// 8-phase GEMM + Yat epilogue.
// ---------------------------------------------------------------------------
__global__ __launch_bounds__(512, 2) void yat_gemm(const bf16_t* __restrict__ A,   // [M,K] bf16 (ws)
                                                   const bf16_t* __restrict__ Bw,  // [N,K] bf16 (ws)
                                                   const float* __restrict__ xsq,  // [M]
                                                   const float* __restrict__ wsq,  // [N]
                                                   const float* __restrict__ bias,   // [N] fp32
                                                   const float* __restrict__ alpha,  // [1] fp32
                                                   float* __restrict__ out) {        // [M,N] fp32
    __shared__ bf16_t sA[4 * SEG];  // 64 KB, ring of 4 A row-half segs
    __shared__ bf16_t sB[4 * SEG];  // 64 KB, ring of 4 B row-half segs

    const int tid = (int)threadIdx.x;
    const int lane = tid & 63;
    const int wv = tid >> 6;   // 0..7
    const int wm = wv >> 2;    // 0..1 : wave row (128-row band)
    const int wn = wv & 3;     // 0..3 : wave col (64-col band)

    const int bm = (int)blockIdx.x >> 3;  // 0..63
    const int bn = (int)blockIdx.x & 7;   // 0..7

    // fragment addressing (mfma_f32_16x16x32_bf16):
    //  A: lane holds A[m=lane&15][k=(lane>>4)*8+j]; B mirrored ([n][k])
    //  C/D: col=lane&15, row=(lane>>4)*4+reg   [m89/m91-verified]
    const int frm = lane & 15;
    const int jch = lane >> 4;  // k-chunk 0..3 within a K=32 group
    const int sx = frm & 7;     // row-XOR for LDS swizzle

    // staging: thread t covers phys chunk (t&7) of seg row (t>>3) (+64 for
    // second load). LDS dest is LINEAR (t*16 B) as global_load_lds requires;
    // the global source chunk is inverse-permuted: g = (t&7) ^ (row&7).
    const int st_r = tid >> 3;  // 0..63
    const int st_g = (tid & 7) ^ (st_r & 7);
    const bf16_t* Ast = A + (size_t)(bm * BM + st_r) * K_DIM + st_g * 8;
    const bf16_t* Bst = Bw + (size_t)(bn * BN + st_r) * K_DIM + st_g * 8;

    auto stageA = [&](int kt, int h) {
        if (kt >= KT) return;
        bf16_t* d = sA + ((kt * 2 + h) & 3) * SEG + tid * 8;
        const bf16_t* s = Ast + (size_t)(h * 128) * K_DIM + kt * 64;
        async16(s, d);
        async16(s + (size_t)64 * K_DIM, d + 4096);
    };
    auto stageB = [&](int kt, int h) {
        if (kt >= KT) return;
        bf16_t* d = sB + ((kt * 2 + h) & 3) * SEG + tid * 8;
        const bf16_t* s = Bst + (size_t)(h * 128) * K_DIM + kt * 64;
        async16(s, d);
        async16(s + (size_t)64 * K_DIM, d + 4096);
    };

    f32x4 acc[8][4] = {};
    bf16x8 bfr[4][2];  // B frags for current K-tile, live across its 4 phases

    // prologue: B(0,*), A(0,*), B(1,*) staged; wait for first 4 segs.
    stageB(0, 0); stageB(0, 1);
    stageA(0, 0); stageA(0, 1);
    stageB(1, 0); stageB(1, 1);
    asm volatile("s_waitcnt vmcnt(4)" ::: "memory");
    asm volatile("s_barrier" ::: "memory");

// Phase: Q = m-quadrant (compile-time literal -> static acc indexing),
// KTT = K-tile computed, SMAT/SKT/SH = seg staged this phase,
// VMEND = counted vmcnt before closing barrier (phases 4 and 8).
#define PHASE(Q, KTT, SMAT, SKT, SH, VMEND)                                     \
    {                                                                           \
        if ((Q) == 0) {                                                         \
            const int bslot = (((KTT) * 2 + (wn >> 1)) & 3) * SEG;              \
            _Pragma("unroll") for (int j = 0; j < 4; ++j) {                     \
                const int brow = (wn & 1) * 64 + j * 16 + frm;                  \
                _Pragma("unroll") for (int kk = 0; kk < 2; ++kk)                \
                    bfr[j][kk] = *(const bf16x8*)&sB[bslot + brow * 64 +        \
                                                    (((kk * 4 + jch) ^ sx) * 8)]; \
            }                                                                   \
        }                                                                       \
        bf16x8 af[2][2];                                                        \
        {                                                                       \
            const int aslot = (((KTT) * 2 + wm) & 3) * SEG;                     \
            _Pragma("unroll") for (int i2 = 0; i2 < 2; ++i2) {                  \
                const int arow = ((Q) * 2 + i2) * 16 + frm;                     \
                _Pragma("unroll") for (int kk = 0; kk < 2; ++kk)                \
                    af[i2][kk] = *(const bf16x8*)&sA[aslot + arow * 64 +        \
                                                    (((kk * 4 + jch) ^ sx) * 8)]; \
            }                                                                   \
        }                                                                       \
        if ((SMAT) == 0) stageA((SKT), (SH)); else stageB((SKT), (SH));         \
        asm volatile("s_barrier" ::: "memory");                                 \
        __builtin_amdgcn_s_setprio(1);                                          \
        _Pragma("unroll") for (int kk = 0; kk < 2; ++kk)                        \
            _Pragma("unroll") for (int i2 = 0; i2 < 2; ++i2)                    \
                _Pragma("unroll") for (int j = 0; j < 4; ++j)                   \
                    acc[(Q) * 2 + i2][j] = __builtin_amdgcn_mfma_f32_16x16x32_bf16( \
                        af[i2][kk], bfr[j][kk], acc[(Q) * 2 + i2][j], 0, 0, 0); \
        __builtin_amdgcn_s_setprio(0);                                          \
        if (VMEND) {                                                            \
            if ((SKT) >= KT) { asm volatile("s_waitcnt vmcnt(0)" ::: "memory"); } \
            else             { asm volatile("s_waitcnt vmcnt(4)" ::: "memory"); } \
        }                                                                       \
        asm volatile("s_barrier" ::: "memory");                                 \
    }

#pragma unroll 1
    for (int u = 0; u < KT / 2; ++u) {
        const int a = 2 * u, b = 2 * u + 1;
        PHASE(0, a, 0, b,     0, 0)   // p1: stage A(b,0)
        PHASE(1, a, 0, b,     1, 0)   // p2: stage A(b,1)
        PHASE(2, a, 1, a + 2, 0, 0)   // p3: stage B(a+2,0)
        PHASE(3, a, 1, a + 2, 1, 1)   // p4: stage B(a+2,1), vmcnt
        PHASE(0, b, 0, a + 2, 0, 0)   // p5: stage A(a+2,0)
        PHASE(1, b, 0, a + 2, 1, 0)   // p6: stage A(a+2,1)
        PHASE(2, b, 1, b + 2, 0, 0)   // p7: stage B(b+2,0)
        PHASE(3, b, 1, b + 2, 1, 1)   // p8: stage B(b+2,1), vmcnt
    }
#undef PHASE

    // epilogue (fp32 stores)
    const float sc = powf(sqrtf((float)N_DIM) / logf(1.0f + (float)N_DIM), alpha[0]);
    float wsq_c[4], bias_c[4];
#pragma unroll
    for (int j = 0; j < 4; ++j) {
        const int col = bn * BN + wn * 64 + j * 16 + frm;
        wsq_c[j] = wsq[col];
        bias_c[j] = bias[col];
    }
#pragma unroll
    for (int i = 0; i < 8; ++i) {
#pragma unroll
        for (int r = 0; r < 4; ++r) {
            const int row = bm * BM + wm * 128 + i * 16 + jch * 4 + r;
            const float xs = xsq[row];
            float* orow = out + (size_t)row * N_DIM + bn * BN + wn * 64 + frm;
#pragma unroll
            for (int j = 0; j < 4; ++j) {
                const float y = acc[i][j][r];
                const float d = xs + wsq_c[j] - 2.0f * y + 1e-6f;
                orow[j * 16] = (y * y) / d * sc + bias_c[j];
            }
        }
    }
}

extern "C" void kernel_launch(void* const* d_in, const int* in_sizes, int n_in,
                              void* d_out, int out_size, void* d_ws, size_t ws_size,
                              hipStream_t stream) {
    (void)in_sizes; (void)n_in; (void)out_size; (void)ws_size;
    const float* x = (const float*)d_in[0];      // [16384, 2048] fp32
    const float* w = (const float*)d_in[1];      // [2048, 2048] fp32
    const float* alpha = (const float*)d_in[2];  // [1] fp32
    const float* bias = (const float*)d_in[3];   // [2048] fp32
    float* out = (float*)d_out;                  // [16384, 2048] fp32

    // ws layout: xb (33.5M bf16), wb (4.2M bf16), xsq (16384 f32), wsq (2048 f32)
    bf16_t* xb = (bf16_t*)d_ws;
    bf16_t* wb = xb + (size_t)M_DIM * K_DIM;
    float* xsq = (float*)(wb + (size_t)N_DIM * K_DIM);
    float* wsq = xsq + M_DIM;

    prep_convert<<<M_DIM + N_DIM, 256, 0, stream>>>(x, w, xb, wb, xsq, wsq);
    yat_gemm<<<(M_DIM / BM) * (N_DIM / BN), 512, 0, stream>>>(xb, wb, xsq, wsq, bias, alpha, out);
}